// Round 2
// baseline (642.836 us; speedup 1.0000x reference)
//
#include <hip/hip_runtime.h>

// Problem constants (fixed by reference setup_inputs)
#define N_ROWS   65536      // 32*2048 flattened rows
#define D        256        // embedding_dim
#define D4       64         // D/4 in float4 units
#define M        1024       // n_embeddings
#define BM       64         // rows per block (argmin kernel)
#define BN       64         // codes per j-tile
#define BK       32         // K chunk
#define XS_STRIDE 68        // BM + 4 pad: 16B-aligned ds_read_b128, breaks bank aliasing
#define LOSS_OFF 16777216   // d_out offset of loss scalar
#define IDX_OFF  16777217   // d_out offset of indices (as float)
#define COMMIT_SCALE (0.25f / 16777216.0f)  // COMMITMENT_COST / numel(x)

// ===== numpy-exact fp32 row-norm emulation ================================
// np.sum(v*v, axis=-1) for n=256 contiguous fp32 on an AVX-512 host:
//   pairwise split 256 -> 128 + 128; each 128-block: 8 zmm accumulators
//   (here: 8 chain terms per lane l=0..15), combined ((r0+r1)+(r2+r3))+
//   ((r4+r5)+(r6+r7)) lanewise, then _mm512_reduce_add_ps halving tree:
//   +8, +4, then (t0+t2)+(t1+t3). Finally block0 + block1 (scalar fadd).
// All adds/muls via __f*_rn so the compiler can't contract or reassociate.
__device__ __forceinline__ float np_block128(const float* __restrict__ a, int l) {
    float r0 = __fmul_rn(a[l +   0], a[l +   0]);
    float r1 = __fmul_rn(a[l +  16], a[l +  16]);
    float r2 = __fmul_rn(a[l +  32], a[l +  32]);
    float r3 = __fmul_rn(a[l +  48], a[l +  48]);
    float r4 = __fmul_rn(a[l +  64], a[l +  64]);
    float r5 = __fmul_rn(a[l +  80], a[l +  80]);
    float r6 = __fmul_rn(a[l +  96], a[l +  96]);
    float r7 = __fmul_rn(a[l + 112], a[l + 112]);
    return __fadd_rn(__fadd_rn(__fadd_rn(r0, r1), __fadd_rn(r2, r3)),
                     __fadd_rn(__fadd_rn(r4, r5), __fadd_rn(r6, r7)));
}

// _mm512_reduce_add_ps tree across the 16 "lanes" (valid result on l==0):
// s1[l]=v[l]+v[l+8]; s2[l]=s1[l]+s1[l+4]; final=(s2[0]+s2[2])+(s2[1]+s2[3])
__device__ __forceinline__ float np_reduce16(float v) {
    float s = __fadd_rn(v, __shfl_down(v, 8));
    s = __fadd_rn(s, __shfl_down(s, 4));
    s = __fadd_rn(s, __shfl_down(s, 2));   // lane0: t0+t2, lane1: t1+t3
    s = __fadd_rn(s, __shfl_down(s, 1));   // lane0: (t0+t2)+(t1+t3)
    return s;
}

// ---------------- kernel 1: np-exact row norms for x and emb --------------
// 256 threads = 16 groups of 16 lanes; one row per group.
// Blocks [0,4096) -> x rows; blocks [4096,4160) -> emb rows.
__global__ __launch_bounds__(256) void norms_kernel(
    const float* __restrict__ x, const float* __restrict__ emb,
    float* __restrict__ bsq, float* __restrict__ esq,
    float* __restrict__ loss_slot) {
    const int tid = threadIdx.x;
    const int l = tid & 15, g = tid >> 4;
    const float* src;
    float* dst;
    if (blockIdx.x < 4096) {
        const int row = blockIdx.x * 16 + g;
        src = x + (size_t)row * D;
        dst = bsq + row;
    } else {
        const int row = (blockIdx.x - 4096) * 16 + g;
        src = emb + (size_t)row * D;
        dst = esq + row;
    }
    const float v0 = np_block128(src, l);
    const float v1 = np_block128(src + 128, l);
    const float t0 = np_reduce16(v0);
    const float t1 = np_reduce16(v1);
    if (l == 0) *dst = __fadd_rn(t0, t1);
    if (blockIdx.x == 0 && tid == 0) *loss_slot = 0.0f;  // d_out is poisoned
}

// ---------------- kernel 2: fused distances + argmin ----------------------
// Replicates the reference's fp32 rounding: d = fl(fl(esq_j + xsq_i) - 2*C).
// C accumulated in fp32 (|delta| vs BLAS ~4e-9 << 1.5e-5 grid step).
__global__ __launch_bounds__(256) void argmin_kernel(
    const float* __restrict__ x, const float* __restrict__ emb,
    const float* __restrict__ esq, const float* __restrict__ bsq,
    float* __restrict__ idx_out_f, int* __restrict__ idx_out_i) {
    __shared__ float xs[BK * XS_STRIDE];   // K-major x tile: xs[k][r]
    __shared__ float es[BK * XS_STRIDE];   // K-major e tile: es[k][j]
    __shared__ float esq_s[BN];
    __shared__ float bsq_s[BM];
    __shared__ float redd[BM * 16];
    __shared__ int   redi[BM * 16];

    const int tid  = threadIdx.x;
    const int tx   = tid & 15;             // j-group: codes tx*4..tx*4+3
    const int ty   = tid >> 4;             // row-group: rows ty*4..ty*4+3
    const int row0 = blockIdx.x * BM;

    if (tid < BM) bsq_s[tid] = bsq[row0 + tid];   // sync'd by first barrier below

    float best[4] = {3.0e38f, 3.0e38f, 3.0e38f, 3.0e38f};
    int   bidx[4] = {0, 0, 0, 0};

    for (int jt = 0; jt < M / BN; ++jt) {
        const int j0 = jt * BN;
        __syncthreads();                   // protect esq_s/xs/es from prior readers
        if (tid < BN) esq_s[tid] = esq[j0 + tid];

        float acc[4][4] = {};
        for (int kc = 0; kc < D / BK; ++kc) {
            const int k0 = kc * BK;
            if (kc) __syncthreads();       // jt-top sync covers kc==0
            #pragma unroll
            for (int h = 0; h < 2; ++h) {
                const int f  = tid + h * 256;   // 0..511
                const int r  = f >> 3;          // 0..63
                const int kk = (f & 7) * 4;
                float4 v = *(const float4*)&x[(row0 + r) * D + k0 + kk];
                xs[(kk + 0) * XS_STRIDE + r] = v.x;
                xs[(kk + 1) * XS_STRIDE + r] = v.y;
                xs[(kk + 2) * XS_STRIDE + r] = v.z;
                xs[(kk + 3) * XS_STRIDE + r] = v.w;
                float4 w = *(const float4*)&emb[(j0 + r) * D + k0 + kk];
                es[(kk + 0) * XS_STRIDE + r] = w.x;
                es[(kk + 1) * XS_STRIDE + r] = w.y;
                es[(kk + 2) * XS_STRIDE + r] = w.z;
                es[(kk + 3) * XS_STRIDE + r] = w.w;
            }
            __syncthreads();
            #pragma unroll
            for (int k = 0; k < BK; ++k) {
                float4 a = *(const float4*)&xs[k * XS_STRIDE + ty * 4];
                float4 b = *(const float4*)&es[k * XS_STRIDE + tx * 4];
                acc[0][0] += a.x * b.x; acc[0][1] += a.x * b.y;
                acc[0][2] += a.x * b.z; acc[0][3] += a.x * b.w;
                acc[1][0] += a.y * b.x; acc[1][1] += a.y * b.y;
                acc[1][2] += a.y * b.z; acc[1][3] += a.y * b.w;
                acc[2][0] += a.z * b.x; acc[2][1] += a.z * b.y;
                acc[2][2] += a.z * b.z; acc[2][3] += a.z * b.w;
                acc[3][0] += a.w * b.x; acc[3][1] += a.w * b.y;
                acc[3][2] += a.w * b.z; acc[3][3] += a.w * b.w;
            }
        }
        // Epilogue: reference-rounded distance, running argmin.
        // Ascending j + strict < keeps lowest index on (common) grid ties.
        #pragma unroll
        for (int i = 0; i < 4; ++i) {
            const float bq = bsq_s[ty * 4 + i];
            #pragma unroll
            for (int jj = 0; jj < 4; ++jj) {
                const float t1 = __fadd_rn(esq_s[tx * 4 + jj], bq);
                const float d  = __fsub_rn(t1, 2.0f * acc[i][jj]);
                const int   j  = j0 + tx * 4 + jj;
                if (d < best[i]) { best[i] = d; bidx[i] = j; }
            }
        }
    }
    __syncthreads();
    #pragma unroll
    for (int i = 0; i < 4; ++i) {
        const int r = ty * 4 + i;
        redd[r * 16 + tx] = best[i];
        redi[r * 16 + tx] = bidx[i];
    }
    __syncthreads();
    if (tid < BM) {
        const int r = tid;
        float bd = redd[r * 16];
        int   bi = redi[r * 16];
        for (int t = 1; t < 16; ++t) {
            const float d  = redd[r * 16 + t];
            const int   ji = redi[r * 16 + t];
            if (d < bd || (d == bd && ji < bi)) { bd = d; bi = ji; }
        }
        idx_out_f[row0 + r] = (float)bi;
        idx_out_i[row0 + r] = bi;
    }
}

// ---------------- kernel 3: gather quantized + commitment loss ------------
__global__ __launch_bounds__(256) void gather_loss_kernel(
    const float4* __restrict__ x4, const float4* __restrict__ emb4,
    const int* __restrict__ idx, float4* __restrict__ q4,
    float* __restrict__ loss_slot) {
    const int base = blockIdx.x * 256 + threadIdx.x;
    float acc = 0.0f;
    #pragma unroll
    for (int i = 0; i < 16; ++i) {
        const int f   = base + i * (1024 * 256);
        const int row = f >> 6;
        const int c4  = f & 63;
        const int e   = idx[row];                  // wave-uniform (64 f4/row)
        float4 q  = emb4[e * D4 + c4];
        float4 xv = x4[f];
        q4[f] = q;
        const float dx = xv.x - q.x, dy = xv.y - q.y;
        const float dz = xv.z - q.z, dw = xv.w - q.w;
        acc += dx * dx + dy * dy + dz * dz + dw * dw;
    }
    #pragma unroll
    for (int off = 32; off; off >>= 1) acc += __shfl_down(acc, off, 64);
    __shared__ float wsum[4];
    const int lane = threadIdx.x & 63, w = threadIdx.x >> 6;
    if (lane == 0) wsum[w] = acc;
    __syncthreads();
    if (threadIdx.x == 0) {
        const float s = wsum[0] + wsum[1] + wsum[2] + wsum[3];
        atomicAdd(loss_slot, s * COMMIT_SCALE);
    }
}

extern "C" void kernel_launch(void* const* d_in, const int* in_sizes, int n_in,
                              void* d_out, int out_size, void* d_ws, size_t ws_size,
                              hipStream_t stream) {
    const float* x   = (const float*)d_in[0];    // 32*2048*256
    const float* emb = (const float*)d_in[1];    // 1024*256
    float* out = (float*)d_out;
    float* bsq = (float*)d_ws;                                   // N_ROWS floats
    float* esq = bsq + N_ROWS;                                   // M floats
    int*   idx = (int*)(esq + M);                                // N_ROWS ints

    norms_kernel<<<4096 + M / 16, 256, 0, stream>>>(x, emb, bsq, esq,
                                                    out + LOSS_OFF);
    argmin_kernel<<<N_ROWS / BM, 256, 0, stream>>>(x, emb, esq, bsq,
                                                   out + IDX_OFF, idx);
    gather_loss_kernel<<<1024, 256, 0, stream>>>((const float4*)x,
                                                 (const float4*)emb, idx,
                                                 (float4*)out, out + LOSS_OFF);
}

// Round 3
// 253.513 us; speedup vs baseline: 2.5357x; 2.5357x over previous
//
#include <hip/hip_runtime.h>

// Problem constants (fixed by reference setup_inputs)
#define N_ROWS   65536      // 32*2048 flattened rows
#define D        256        // embedding_dim
#define D4       64         // D/4 in float4 units
#define M        1024       // n_embeddings
#define LOSS_OFF 16777216   // d_out offset of loss scalar
#define IDX_OFF  16777217   // d_out offset of indices (as float)
#define COMMIT_SCALE (0.25f / 16777216.0f)  // COMMITMENT_COST / numel(x)
#define E_SCALE  1024.0f    // exact pow2 pre-scale of e so e' in [-1,1]
#define C_SCALE  0.001953125f  // 2/1024: acc*C_SCALE == 2*C exactly

typedef _Float16 f16x8 __attribute__((ext_vector_type(8)));
typedef _Float16 f16x4 __attribute__((ext_vector_type(4)));
typedef float    f32x4 __attribute__((ext_vector_type(4)));

// ===== numpy-exact fp32 row-norm emulation (unchanged from round 2; PASSED)
__device__ __forceinline__ float np_block128(const float* __restrict__ a, int l) {
    float r0 = __fmul_rn(a[l +   0], a[l +   0]);
    float r1 = __fmul_rn(a[l +  16], a[l +  16]);
    float r2 = __fmul_rn(a[l +  32], a[l +  32]);
    float r3 = __fmul_rn(a[l +  48], a[l +  48]);
    float r4 = __fmul_rn(a[l +  64], a[l +  64]);
    float r5 = __fmul_rn(a[l +  80], a[l +  80]);
    float r6 = __fmul_rn(a[l +  96], a[l +  96]);
    float r7 = __fmul_rn(a[l + 112], a[l + 112]);
    return __fadd_rn(__fadd_rn(__fadd_rn(r0, r1), __fadd_rn(r2, r3)),
                     __fadd_rn(__fadd_rn(r4, r5), __fadd_rn(r6, r7)));
}
__device__ __forceinline__ float np_reduce16(float v) {
    float s = __fadd_rn(v, __shfl_down(v, 8));
    s = __fadd_rn(s, __shfl_down(s, 4));
    s = __fadd_rn(s, __shfl_down(s, 2));
    s = __fadd_rn(s, __shfl_down(s, 1));
    return s;
}

// ---------------- kernel 1: np-exact row norms for x and emb --------------
__global__ __launch_bounds__(256) void norms_kernel(
    const float* __restrict__ x, const float* __restrict__ emb,
    float* __restrict__ bsq, float* __restrict__ esq,
    float* __restrict__ loss_slot) {
    const int tid = threadIdx.x;
    const int l = tid & 15, g = tid >> 4;
    const float* src;
    float* dst;
    if (blockIdx.x < 4096) {
        const int row = blockIdx.x * 16 + g;
        src = x + (size_t)row * D;
        dst = bsq + row;
    } else {
        const int row = (blockIdx.x - 4096) * 16 + g;
        src = emb + (size_t)row * D;
        dst = esq + row;
    }
    const float v0 = np_block128(src, l);
    const float v1 = np_block128(src + 128, l);
    const float t0 = np_reduce16(v0);
    const float t1 = np_reduce16(v1);
    if (l == 0) *dst = __fadd_rn(t0, t1);
    if (blockIdx.x == 0 && tid == 0) *loss_slot = 0.0f;  // d_out is poisoned
}

// ---------------- kernel 2: split e' = 1024*e into fp16 hi/mid planes -----
// e' in [-1,1]: hi captures 11 bits, mid the next 11 -> residual ~2^-22 rel,
// negligible vs the reference's ~2^-20.6 distance grid.
__global__ __launch_bounds__(256) void esplit_kernel(
    const float4* __restrict__ emb4,
    _Float16* __restrict__ e_hi, _Float16* __restrict__ e_mid) {
    const int f = blockIdx.x * 256 + threadIdx.x;   // 0..65535 float4s
    float4 v = emb4[f];
    float a[4] = {v.x * E_SCALE, v.y * E_SCALE, v.z * E_SCALE, v.w * E_SCALE};
    f16x4 hi, mid;
    #pragma unroll
    for (int j = 0; j < 4; ++j) {
        _Float16 h = (_Float16)a[j];
        float r = __fsub_rn(a[j], (float)h);
        hi[j] = h;
        mid[j] = (_Float16)r;
    }
    *(f16x4*)&e_hi[f * 4]  = hi;
    *(f16x4*)&e_mid[f * 4] = mid;
}

// ---------------- kernel 3: fp16-split MFMA distances + argmin ------------
// Block: 64 rows x all 1024 codes. 4 waves in 2x2: wave = 32 rows x 64 codes.
// A (x) fragments for the FULL K=256 held in registers (hi+mid = 128 VGPRs);
// B (e-splits) streamed global -> LDS in [128 codes][32 k] chunks.
// 3 MFMA passes per chunk: hi*hi + mid*hi + hi*mid (acc = 1024 * x.e).
__global__ __launch_bounds__(256, 2) void argmin_mfma_kernel(
    const float* __restrict__ x,
    const _Float16* __restrict__ e_hi, const _Float16* __restrict__ e_mid,
    const float* __restrict__ esq, const float* __restrict__ bsq,
    float* __restrict__ idx_out_f, int* __restrict__ idx_out_i) {
    __shared__ _Float16 bs[2][128 * 40];   // stride 40 f16 = 20 dwords: conflict-free
    __shared__ float red_d[64][2];
    __shared__ int   red_i[64][2];

    const int tid = threadIdx.x;
    const int w = tid >> 6, lane = tid & 63;
    const int w_row = w >> 1, w_col = w & 1;
    const int lm = lane & 15, q = lane >> 4;     // A/B frag: [lm][k=q*8+j]
    const int row0 = blockIdx.x * 64;

    // ---- A fragments: rows row0 + w_row*32 + fm*16 + lm, split on the fly
    f16x8 a_hi[2][8], a_mid[2][8];
    #pragma unroll
    for (int fm = 0; fm < 2; ++fm) {
        const float* xr = x + (size_t)(row0 + w_row * 32 + fm * 16 + lm) * D + q * 8;
        #pragma unroll
        for (int kc = 0; kc < 8; ++kc) {
            float4 v0 = *(const float4*)(xr + kc * 32);
            float4 v1 = *(const float4*)(xr + kc * 32 + 4);
            float e[8] = {v0.x, v0.y, v0.z, v0.w, v1.x, v1.y, v1.z, v1.w};
            #pragma unroll
            for (int j = 0; j < 8; ++j) {
                _Float16 h = (_Float16)e[j];
                float r = __fsub_rn(e[j], (float)h);
                a_hi[fm][kc][j]  = h;
                a_mid[fm][kc][j] = (_Float16)r;
            }
        }
    }
    // bsq for this lane's 8 (fm,reg) C-rows
    float bq[2][4];
    #pragma unroll
    for (int fm = 0; fm < 2; ++fm)
        #pragma unroll
        for (int r = 0; r < 4; ++r)
            bq[fm][r] = bsq[row0 + w_row * 32 + fm * 16 + q * 4 + r];

    float best[2][4] = {{3.0e38f, 3.0e38f, 3.0e38f, 3.0e38f},
                        {3.0e38f, 3.0e38f, 3.0e38f, 3.0e38f}};
    int bidx[2][4] = {{0, 0, 0, 0}, {0, 0, 0, 0}};

    const int sc = tid >> 1;       // staging: code 0..127
    const int sh = tid & 1;        // staging: 16-element half of the 32-k chunk

    for (int jt = 0; jt < 8; ++jt) {
        const int j0 = jt * 128;
        f32x4 acc[2][4] = {};
        #pragma unroll
        for (int kc = 0; kc < 8; ++kc) {
            __syncthreads();       // previous chunk's readers done
            const size_t gofs = (size_t)(j0 + sc) * D + kc * 32 + sh * 16;
            _Float16* dh = &bs[0][sc * 40 + sh * 16];
            _Float16* dm = &bs[1][sc * 40 + sh * 16];
            *(uint4*)(dh)     = *(const uint4*)(e_hi + gofs);
            *(uint4*)(dh + 8) = *(const uint4*)(e_hi + gofs + 8);
            *(uint4*)(dm)     = *(const uint4*)(e_mid + gofs);
            *(uint4*)(dm + 8) = *(const uint4*)(e_mid + gofs + 8);
            __syncthreads();
            f16x8 bh[4], bm[4];
            #pragma unroll
            for (int fn = 0; fn < 4; ++fn) {
                const int bo = (w_col * 64 + fn * 16 + lm) * 40 + q * 8;
                bh[fn] = *(const f16x8*)&bs[0][bo];
                bm[fn] = *(const f16x8*)&bs[1][bo];
            }
            #pragma unroll
            for (int fm = 0; fm < 2; ++fm)
                #pragma unroll
                for (int fn = 0; fn < 4; ++fn) {
                    acc[fm][fn] = __builtin_amdgcn_mfma_f32_16x16x32_f16(
                        a_hi[fm][kc], bh[fn], acc[fm][fn], 0, 0, 0);
                    acc[fm][fn] = __builtin_amdgcn_mfma_f32_16x16x32_f16(
                        a_mid[fm][kc], bh[fn], acc[fm][fn], 0, 0, 0);
                    acc[fm][fn] = __builtin_amdgcn_mfma_f32_16x16x32_f16(
                        a_hi[fm][kc], bm[fn], acc[fm][fn], 0, 0, 0);
                }
        }
        // Epilogue: reference-rounded d, running argmin (ascending j, strict <)
        #pragma unroll
        for (int fn = 0; fn < 4; ++fn) {
            const int j = j0 + w_col * 64 + fn * 16 + lm;
            const float eq = esq[j];
            #pragma unroll
            for (int fm = 0; fm < 2; ++fm)
                #pragma unroll
                for (int r = 0; r < 4; ++r) {
                    const float d = __fsub_rn(__fadd_rn(eq, bq[fm][r]),
                                              acc[fm][fn][r] * C_SCALE);
                    if (d < best[fm][r]) { best[fm][r] = d; bidx[fm][r] = j; }
                }
        }
    }
    // Reduce across the 16 col-lanes of each quad (lexicographic min)
    #pragma unroll
    for (int fm = 0; fm < 2; ++fm)
        #pragma unroll
        for (int r = 0; r < 4; ++r) {
            float d = best[fm][r]; int i = bidx[fm][r];
            #pragma unroll
            for (int mv = 1; mv <= 8; mv <<= 1) {
                const float d2 = __shfl_xor(d, mv, 64);
                const int   i2 = __shfl_xor(i, mv, 64);
                if (d2 < d || (d2 == d && i2 < i)) { d = d2; i = i2; }
            }
            best[fm][r] = d; bidx[fm][r] = i;
        }
    __syncthreads();
    if (lm == 0) {
        #pragma unroll
        for (int fm = 0; fm < 2; ++fm)
            #pragma unroll
            for (int r = 0; r < 4; ++r) {
                const int rl = w_row * 32 + fm * 16 + q * 4 + r;
                red_d[rl][w_col] = best[fm][r];
                red_i[rl][w_col] = bidx[fm][r];
            }
    }
    __syncthreads();
    if (tid < 64) {
        float d0 = red_d[tid][0]; int i0 = red_i[tid][0];
        const float d1 = red_d[tid][1]; const int i1 = red_i[tid][1];
        if (d1 < d0 || (d1 == d0 && i1 < i0)) { d0 = d1; i0 = i1; }
        idx_out_f[row0 + tid] = (float)i0;
        idx_out_i[row0 + tid] = i0;
    }
}

// ---------------- kernel 4: gather quantized + commitment loss ------------
__global__ __launch_bounds__(256) void gather_loss_kernel(
    const float4* __restrict__ x4, const float4* __restrict__ emb4,
    const int* __restrict__ idx, float4* __restrict__ q4,
    float* __restrict__ loss_slot) {
    const int base = blockIdx.x * 256 + threadIdx.x;
    float acc = 0.0f;
    #pragma unroll
    for (int i = 0; i < 16; ++i) {
        const int f   = base + i * (1024 * 256);
        const int row = f >> 6;
        const int c4  = f & 63;
        const int e   = idx[row];                  // wave-uniform (64 f4/row)
        float4 qv = emb4[e * D4 + c4];
        float4 xv = x4[f];
        q4[f] = qv;
        const float dx = xv.x - qv.x, dy = xv.y - qv.y;
        const float dz = xv.z - qv.z, dw = xv.w - qv.w;
        acc += dx * dx + dy * dy + dz * dz + dw * dw;
    }
    #pragma unroll
    for (int off = 32; off; off >>= 1) acc += __shfl_down(acc, off, 64);
    __shared__ float wsum[4];
    const int lane = threadIdx.x & 63, w = threadIdx.x >> 6;
    if (lane == 0) wsum[w] = acc;
    __syncthreads();
    if (threadIdx.x == 0) {
        atomicAdd(loss_slot, (wsum[0] + wsum[1] + wsum[2] + wsum[3]) * COMMIT_SCALE);
    }
}

extern "C" void kernel_launch(void* const* d_in, const int* in_sizes, int n_in,
                              void* d_out, int out_size, void* d_ws, size_t ws_size,
                              hipStream_t stream) {
    const float* x   = (const float*)d_in[0];    // 32*2048*256
    const float* emb = (const float*)d_in[1];    // 1024*256
    float* out = (float*)d_out;
    // ws layout (all 16B-aligned): bsq | esq | idx | e_hi | e_mid
    float*    bsq  = (float*)d_ws;                       // N_ROWS f32
    float*    esq  = bsq + N_ROWS;                       // M f32
    int*      idx  = (int*)(esq + M);                    // N_ROWS i32
    _Float16* e_hi = (_Float16*)(idx + N_ROWS);          // M*D f16
    _Float16* e_mid = e_hi + (size_t)M * D;              // M*D f16

    norms_kernel<<<4096 + M / 16, 256, 0, stream>>>(x, emb, bsq, esq,
                                                    out + LOSS_OFF);
    esplit_kernel<<<M * D / 4 / 256, 256, 0, stream>>>((const float4*)emb,
                                                       e_hi, e_mid);
    argmin_mfma_kernel<<<N_ROWS / 64, 256, 0, stream>>>(x, e_hi, e_mid,
                                                        esq, bsq,
                                                        out + IDX_OFF, idx);
    gather_loss_kernel<<<1024, 256, 0, stream>>>((const float4*)x,
                                                 (const float4*)emb, idx,
                                                 (float4*)out, out + LOSS_OFF);
}

// Round 4
// 251.222 us; speedup vs baseline: 2.5588x; 1.0091x over previous
//
#include <hip/hip_runtime.h>

// Problem constants (fixed by reference setup_inputs)
#define N_ROWS   65536      // 32*2048 flattened rows
#define D        256        // embedding_dim
#define D4       64         // D/4 in float4 units
#define M        1024       // n_embeddings
#define LOSS_OFF 16777216   // d_out offset of loss scalar
#define IDX_OFF  16777217   // d_out offset of indices (as float)
#define COMMIT_SCALE (0.25f / 16777216.0f)  // COMMITMENT_COST / numel(x)
#define E_SCALE  1024.0f    // exact pow2 pre-scale of e so e' in [-1,1]
#define C_SCALE  0.001953125f  // 2/1024: acc*C_SCALE == 2*C exactly

typedef _Float16 f16x8 __attribute__((ext_vector_type(8)));
typedef _Float16 f16x4 __attribute__((ext_vector_type(4)));
typedef float    f32x4 __attribute__((ext_vector_type(4)));

// Async global->LDS DMA, 16 B/lane: LDS dest = base + lane*16 (HW-implicit).
__device__ __forceinline__ void async_copy16(const void* g, void* l) {
    __builtin_amdgcn_global_load_lds(
        (const __attribute__((address_space(1))) unsigned int*)g,
        (__attribute__((address_space(3))) unsigned int*)l, 16, 0, 0);
}

// ===== numpy-exact fp32 row-norm emulation (validated rounds 2-3) =========
__device__ __forceinline__ float np_block128(const float* __restrict__ a, int l) {
    float r0 = __fmul_rn(a[l +   0], a[l +   0]);
    float r1 = __fmul_rn(a[l +  16], a[l +  16]);
    float r2 = __fmul_rn(a[l +  32], a[l +  32]);
    float r3 = __fmul_rn(a[l +  48], a[l +  48]);
    float r4 = __fmul_rn(a[l +  64], a[l +  64]);
    float r5 = __fmul_rn(a[l +  80], a[l +  80]);
    float r6 = __fmul_rn(a[l +  96], a[l +  96]);
    float r7 = __fmul_rn(a[l + 112], a[l + 112]);
    return __fadd_rn(__fadd_rn(__fadd_rn(r0, r1), __fadd_rn(r2, r3)),
                     __fadd_rn(__fadd_rn(r4, r5), __fadd_rn(r6, r7)));
}
__device__ __forceinline__ float np_reduce16(float v) {
    float s = __fadd_rn(v, __shfl_down(v, 8));
    s = __fadd_rn(s, __shfl_down(s, 4));
    s = __fadd_rn(s, __shfl_down(s, 2));
    s = __fadd_rn(s, __shfl_down(s, 1));
    return s;
}

// ---------------- kernel 1: np-exact row norms (coalesced via LDS) --------
// 16 rows/block. Phase 1: float4-coalesced load into LDS (exact copy).
// Phase 2: 16-lane groups read LDS in the np AVX-512 order (bit-identical).
__global__ __launch_bounds__(256) void norms_kernel(
    const float4* __restrict__ x4, const float4* __restrict__ emb4,
    float* __restrict__ bsq, float* __restrict__ esq,
    float* __restrict__ loss_slot) {
    __shared__ float rowbuf[16 * 260];   // stride 260: conflict-free np reads
    const int tid = threadIdx.x;
    const float4* src4;
    float* dst;
    int row0;
    if (blockIdx.x < 4096) {
        row0 = blockIdx.x * 16;
        src4 = x4 + (size_t)row0 * 64;
        dst = bsq + row0;
    } else {
        row0 = (blockIdx.x - 4096) * 16;
        src4 = emb4 + (size_t)row0 * 64;
        dst = esq + row0;
    }
    #pragma unroll
    for (int p = 0; p < 4; ++p) {
        const int f = tid + p * 256;     // 0..1023 float4s = 16 rows
        const int r = f >> 6, c4 = f & 63;
        *(float4*)&rowbuf[r * 260 + c4 * 4] = src4[f];
    }
    __syncthreads();
    const int l = tid & 15, g = tid >> 4;
    const float* base = &rowbuf[g * 260];
    const float v0 = np_block128(base, l);
    const float v1 = np_block128(base + 128, l);
    const float t0 = np_reduce16(v0);
    const float t1 = np_reduce16(v1);
    if (l == 0) dst[g] = __fadd_rn(t0, t1);
    if (blockIdx.x == 0 && tid == 0) *loss_slot = 0.0f;  // d_out is poisoned
}

// ---------------- kernel 2: split e' = 1024*e into CHUNKED fp16 planes ----
// Layout: e_hi[kc][code][k32] (kc = k/32) so each (jt,kc) B-chunk of
// 128 codes x 32 k is 8 KB CONTIGUOUS -> eligible for global_load_lds DMA.
__global__ __launch_bounds__(256) void esplit_kernel(
    const float4* __restrict__ emb4,
    _Float16* __restrict__ e_hi, _Float16* __restrict__ e_mid) {
    const int f = blockIdx.x * 256 + threadIdx.x;   // 0..65535 float4s
    const int code = f >> 6, k4 = f & 63;
    const int kc = k4 >> 3, ko = (k4 & 7) * 4;
    float4 v = emb4[f];
    float a[4] = {v.x * E_SCALE, v.y * E_SCALE, v.z * E_SCALE, v.w * E_SCALE};
    f16x4 hi, mid;
    #pragma unroll
    for (int j = 0; j < 4; ++j) {
        _Float16 h = (_Float16)a[j];
        float r = __fsub_rn(a[j], (float)h);
        hi[j] = h;
        mid[j] = (_Float16)r;
    }
    const size_t ofs = (size_t)kc * (M * 32) + (size_t)code * 32 + ko;
    *(f16x4*)&e_hi[ofs]  = hi;
    *(f16x4*)&e_mid[ofs] = mid;
}

// ---------------- kernel 3: fp16-split MFMA distances + argmin ------------
// Block: 64 rows x all 1024 codes; 4 waves in 2x2 (wave = 32 rows x 64 codes).
// A (x) fragments full-K in registers; B chunks DMA'd global->LDS
// (double-buffered, 1 barrier/chunk, zero ds_writes, conflict-free reads).
// MFMA order identical to round 3 (absmax 0 validated).
__global__ __launch_bounds__(256, 2) void argmin_mfma_kernel(
    const float* __restrict__ x,
    const _Float16* __restrict__ e_hi, const _Float16* __restrict__ e_mid,
    const float* __restrict__ esq, const float* __restrict__ bsq,
    float* __restrict__ idx_out_f, int* __restrict__ idx_out_i) {
    // buf[b]: hi plane f16[0..4096) = [code 0..127][k 0..31], mid at +4096
    __shared__ __attribute__((aligned(16))) _Float16 buf[2][8192];
    __shared__ float red_d[64][2];
    __shared__ int   red_i[64][2];

    const int tid = threadIdx.x;
    const int w = tid >> 6, lane = tid & 63;
    const int w_row = w >> 1, w_col = w & 1;
    const int lm = lane & 15, q = lane >> 4;     // A/B frag: [lm][k=q*8+j]
    const int row0 = blockIdx.x * 64;

    // ---- A fragments: rows row0 + w_row*32 + fm*16 + lm, split on the fly
    f16x8 a_hi[2][8], a_mid[2][8];
    #pragma unroll
    for (int fm = 0; fm < 2; ++fm) {
        const float* xr = x + (size_t)(row0 + w_row * 32 + fm * 16 + lm) * D + q * 8;
        #pragma unroll
        for (int kc = 0; kc < 8; ++kc) {
            float4 v0 = *(const float4*)(xr + kc * 32);
            float4 v1 = *(const float4*)(xr + kc * 32 + 4);
            float e[8] = {v0.x, v0.y, v0.z, v0.w, v1.x, v1.y, v1.z, v1.w};
            #pragma unroll
            for (int j = 0; j < 8; ++j) {
                _Float16 h = (_Float16)e[j];
                float r = __fsub_rn(e[j], (float)h);
                a_hi[fm][kc][j]  = h;
                a_mid[fm][kc][j] = (_Float16)r;
            }
        }
    }
    float bq[2][4];
    #pragma unroll
    for (int fm = 0; fm < 2; ++fm)
        #pragma unroll
        for (int r = 0; r < 4; ++r)
            bq[fm][r] = bsq[row0 + w_row * 32 + fm * 16 + q * 4 + r];

    float best[2][4] = {{3.0e38f, 3.0e38f, 3.0e38f, 3.0e38f},
                        {3.0e38f, 3.0e38f, 3.0e38f, 3.0e38f}};
    int bidx[2][4] = {{0, 0, 0, 0}, {0, 0, 0, 0}};

    // DMA one (jt,kc) chunk: 8 KB hi + 8 KB mid; wave w moves bytes
    // [w*2048, w*2048+2048) of each plane via 2 width-16 instrs.
    auto dma = [&](int c, int bsel) {
        const int jt = c >> 3, kc = c & 7;
        const size_t gofs = (size_t)kc * 65536 + (size_t)jt * 8192
                          + (size_t)w * 2048 + (size_t)lane * 16;   // bytes
        const char* gh = (const char*)e_hi + gofs;
        const char* gm = (const char*)e_mid + gofs;
        _Float16* lh = &buf[bsel][w * 1024];          // byte ofs w*2048
        _Float16* lmm = &buf[bsel][4096 + w * 1024];
        async_copy16(gh, lh);
        async_copy16(gh + 1024, lh + 512);
        async_copy16(gm, lmm);
        async_copy16(gm + 1024, lmm + 512);
    };

    dma(0, 0);
    for (int jt = 0; jt < 8; ++jt) {
        const int j0 = jt * 128;
        f32x4 acc[2][4] = {};
        for (int kc = 0; kc < 8; ++kc) {
            const int c = jt * 8 + kc;
            __syncthreads();               // buf[c&1] DMA landed; other buf free
            if (c < 63) dma(c + 1, (c + 1) & 1);   // prefetch (drained post-MFMA)
            const int bsel = c & 1;
            f16x8 bh[4], bm[4];
            #pragma unroll
            for (int fn = 0; fn < 4; ++fn) {
                const int bo = (w_col * 64 + fn * 16 + lm) * 32 + q * 8;
                bh[fn] = *(const f16x8*)&buf[bsel][bo];          // lane-linear
                bm[fn] = *(const f16x8*)&buf[bsel][4096 + bo];   // conflict-free
            }
            #pragma unroll
            for (int fm = 0; fm < 2; ++fm)
                #pragma unroll
                for (int fn = 0; fn < 4; ++fn) {
                    acc[fm][fn] = __builtin_amdgcn_mfma_f32_16x16x32_f16(
                        a_hi[fm][kc], bh[fn], acc[fm][fn], 0, 0, 0);
                    acc[fm][fn] = __builtin_amdgcn_mfma_f32_16x16x32_f16(
                        a_mid[fm][kc], bh[fn], acc[fm][fn], 0, 0, 0);
                    acc[fm][fn] = __builtin_amdgcn_mfma_f32_16x16x32_f16(
                        a_hi[fm][kc], bm[fn], acc[fm][fn], 0, 0, 0);
                }
        }
        // Epilogue: reference-rounded d, running argmin (ascending j, strict <)
        #pragma unroll
        for (int fn = 0; fn < 4; ++fn) {
            const int j = j0 + w_col * 64 + fn * 16 + lm;
            const float eq = esq[j];
            #pragma unroll
            for (int fm = 0; fm < 2; ++fm)
                #pragma unroll
                for (int r = 0; r < 4; ++r) {
                    const float d = __fsub_rn(__fadd_rn(eq, bq[fm][r]),
                                              acc[fm][fn][r] * C_SCALE);
                    if (d < best[fm][r]) { best[fm][r] = d; bidx[fm][r] = j; }
                }
        }
    }
    // Reduce across the 16 col-lanes of each quad (lexicographic min)
    #pragma unroll
    for (int fm = 0; fm < 2; ++fm)
        #pragma unroll
        for (int r = 0; r < 4; ++r) {
            float d = best[fm][r]; int i = bidx[fm][r];
            #pragma unroll
            for (int mv = 1; mv <= 8; mv <<= 1) {
                const float d2 = __shfl_xor(d, mv, 64);
                const int   i2 = __shfl_xor(i, mv, 64);
                if (d2 < d || (d2 == d && i2 < i)) { d = d2; i = i2; }
            }
            best[fm][r] = d; bidx[fm][r] = i;
        }
    __syncthreads();
    if (lm == 0) {
        #pragma unroll
        for (int fm = 0; fm < 2; ++fm)
            #pragma unroll
            for (int r = 0; r < 4; ++r) {
                const int rl = w_row * 32 + fm * 16 + q * 4 + r;
                red_d[rl][w_col] = best[fm][r];
                red_i[rl][w_col] = bidx[fm][r];
            }
    }
    __syncthreads();
    if (tid < 64) {
        float d0 = red_d[tid][0]; int i0 = red_i[tid][0];
        const float d1 = red_d[tid][1]; const int i1 = red_i[tid][1];
        if (d1 < d0 || (d1 == d0 && i1 < i0)) { d0 = d1; i0 = i1; }
        idx_out_f[row0 + tid] = (float)i0;
        idx_out_i[row0 + tid] = i0;
    }
}

// ---------------- kernel 4: gather quantized + commitment loss ------------
__global__ __launch_bounds__(256) void gather_loss_kernel(
    const float4* __restrict__ x4, const float4* __restrict__ emb4,
    const int* __restrict__ idx, float4* __restrict__ q4,
    float* __restrict__ loss_slot) {
    const int base = blockIdx.x * 256 + threadIdx.x;
    float acc = 0.0f;
    #pragma unroll
    for (int i = 0; i < 16; ++i) {
        const int f   = base + i * (1024 * 256);
        const int row = f >> 6;
        const int c4  = f & 63;
        const int e   = idx[row];                  // wave-uniform (64 f4/row)
        float4 qv = emb4[e * D4 + c4];
        float4 xv = x4[f];
        q4[f] = qv;
        const float dx = xv.x - qv.x, dy = xv.y - qv.y;
        const float dz = xv.z - qv.z, dw = xv.w - qv.w;
        acc += dx * dx + dy * dy + dz * dz + dw * dw;
    }
    #pragma unroll
    for (int off = 32; off; off >>= 1) acc += __shfl_down(acc, off, 64);
    __shared__ float wsum[4];
    const int lane = threadIdx.x & 63, w = threadIdx.x >> 6;
    if (lane == 0) wsum[w] = acc;
    __syncthreads();
    if (threadIdx.x == 0) {
        atomicAdd(loss_slot, (wsum[0] + wsum[1] + wsum[2] + wsum[3]) * COMMIT_SCALE);
    }
}

extern "C" void kernel_launch(void* const* d_in, const int* in_sizes, int n_in,
                              void* d_out, int out_size, void* d_ws, size_t ws_size,
                              hipStream_t stream) {
    const float* x   = (const float*)d_in[0];    // 32*2048*256
    const float* emb = (const float*)d_in[1];    // 1024*256
    float* out = (float*)d_out;
    // ws layout (16B-aligned): bsq | esq | idx | e_hi(chunked) | e_mid(chunked)
    float*    bsq  = (float*)d_ws;                       // N_ROWS f32
    float*    esq  = bsq + N_ROWS;                       // M f32
    int*      idx  = (int*)(esq + M);                    // N_ROWS i32
    _Float16* e_hi = (_Float16*)(idx + N_ROWS);          // M*D f16 chunked
    _Float16* e_mid = e_hi + (size_t)M * D;              // M*D f16 chunked

    norms_kernel<<<4096 + M / 16, 256, 0, stream>>>((const float4*)x,
                                                    (const float4*)emb,
                                                    bsq, esq, out + LOSS_OFF);
    esplit_kernel<<<M * D / 4 / 256, 256, 0, stream>>>((const float4*)emb,
                                                       e_hi, e_mid);
    argmin_mfma_kernel<<<N_ROWS / 64, 256, 0, stream>>>(x, e_hi, e_mid,
                                                        esq, bsq,
                                                        out + IDX_OFF, idx);
    gather_loss_kernel<<<1024, 256, 0, stream>>>((const float4*)x,
                                                 (const float4*)emb, idx,
                                                 (float4*)out, out + LOSS_OFF);
}